// Round 2
// baseline (7000.956 us; speedup 1.0000x reference)
//
#include <hip/hip_runtime.h>
#include <math.h>

#define BB 16
#define NN 512   // seq1 rows = columns of the transposed LSA problem
#define MM 448   // seq2 rows = rows of the transposed LSA problem
#define DD 1536

// ---------------------------------------------------------------------------
// Cost kernel: Ct[b][j][i] = ||seq1[b,i,:] - seq2[b,j,:]||  (float32)
// Unchanged from the passing round-1/2/4/5 version.
// ---------------------------------------------------------------------------
constexpr int TK = 32;

__global__ __launch_bounds__(256) void cost_kernel(const float* __restrict__ s1,
                                                   const float* __restrict__ s2,
                                                   float* __restrict__ Ct) {
  __shared__ float As[TK][68];
  __shared__ float Bs[TK][68];
  const int b = blockIdx.z;
  const int ibase = blockIdx.x * 64;
  const int jbase = blockIdx.y * 64;
  const int tid = threadIdx.x;
  const float* s1b = s1 + ((size_t)b * NN + ibase) * DD;
  const float* s2b = s2 + ((size_t)b * MM + jbase) * DD;
  const int ix = (tid & 15) * 4;
  const int jy = (tid >> 4) * 4;
  double acc[16];
#pragma unroll
  for (int t = 0; t < 16; ++t) acc[t] = 0.0;

  for (int k0 = 0; k0 < DD; k0 += TK) {
#pragma unroll
    for (int rep = 0; rep < 2; ++rep) {
      int idx = tid + rep * 256;
      int r = idx >> 3;
      int c4 = (idx & 7) * 4;
      float4 a = *(const float4*)(s1b + (size_t)r * DD + k0 + c4);
      As[c4 + 0][r] = a.x; As[c4 + 1][r] = a.y; As[c4 + 2][r] = a.z; As[c4 + 3][r] = a.w;
      float4 bb = *(const float4*)(s2b + (size_t)r * DD + k0 + c4);
      Bs[c4 + 0][r] = bb.x; Bs[c4 + 1][r] = bb.y; Bs[c4 + 2][r] = bb.z; Bs[c4 + 3][r] = bb.w;
    }
    __syncthreads();
    float pacc[16];
#pragma unroll
    for (int t = 0; t < 16; ++t) pacc[t] = 0.f;
#pragma unroll 8
    for (int kk = 0; kk < TK; ++kk) {
      float4 av = *(const float4*)&As[kk][ix];
      float4 bv = *(const float4*)&Bs[kk][jy];
      float a[4] = {av.x, av.y, av.z, av.w};
      float bq[4] = {bv.x, bv.y, bv.z, bv.w};
#pragma unroll
      for (int t = 0; t < 4; ++t)
#pragma unroll
        for (int q = 0; q < 4; ++q) {
          float d = a[t] - bq[q];
          pacc[t * 4 + q] = fmaf(d, d, pacc[t * 4 + q]);
        }
    }
#pragma unroll
    for (int t = 0; t < 16; ++t) acc[t] += (double)pacc[t];
    __syncthreads();
  }
#pragma unroll
  for (int t = 0; t < 4; ++t)
#pragma unroll
    for (int q = 0; q < 4; ++q) {
      int i = ibase + ix + t;
      int jj = jbase + jy + q;
      float d2 = (float)acc[t * 4 + q];
      Ct[((size_t)b * MM + jj) * NN + i] = sqrtf(fmaxf(d2, 0.f));
    }
}

// ---------------------------------------------------------------------------
// Cross-lane reduction primitives (DPP shr 1/2/4/8 + bcast 15/31, readlane 63
// broadcast — control pattern verified bit-exact in rounds 1-5, absmax = 0).
// ---------------------------------------------------------------------------
__device__ __forceinline__ unsigned wave_min_bcast_u32(unsigned x) {
  int v = (int)x;
#define ST(C) { int o = __builtin_amdgcn_update_dpp(-1, v, C, 0xF, 0xF, false); \
                v = ((unsigned)o < (unsigned)v) ? o : v; }
  ST(0x111) ST(0x112) ST(0x114) ST(0x118) ST(0x142) ST(0x143)
#undef ST
  return (unsigned)__builtin_amdgcn_readlane(v, 63);
}

__device__ __forceinline__ float wave_min_bcast_f32(float x) {
  union FU { float f; int i; };
  FU v; v.f = x;
  const int INFB = 0x7f7fffff;   // FLT_MAX bit pattern
#define DPP1(CTRL) { FU o; \
  o.i = __builtin_amdgcn_update_dpp(INFB, v.i, CTRL, 0xF, 0xF, false); \
  if (o.f < v.f) v.f = o.f; }
  DPP1(0x111) DPP1(0x112) DPP1(0x114) DPP1(0x118) DPP1(0x142) DPP1(0x143)
#undef DPP1
  FU r; r.i = __builtin_amdgcn_readlane(v.i, 63);
  return r.f;
}

__device__ __forceinline__ double readlane_f64(double x, int sl) {
  union { double d; int i[2]; } v, r;
  v.d = x;
  r.i[0] = __builtin_amdgcn_readlane(v.i[0], sl);
  r.i[1] = __builtin_amdgcn_readlane(v.i[1], sl);
  return r.d;
}

// Exact wave min of NONNEGATIVE f64 + winner lane (lowest lane among exact
// ties). FAST PATH: f64->f32 rounding is monotone, so a UNIQUE lane at the
// f32 wave-min provably holds the exact f64 min -> readlane its f64 bits
// (exact delta, exact winner). Ties at f32 (<1% of calls) fall back to the
// round-1-5-verified two-stage u32 reduce (values nonneg -> bit-order trick).
__device__ __forceinline__ void exact_min_sl(double x, double& mn, int& sl) {
  float xf = (float)x;
  float rf = wave_min_bcast_f32(xf);
  unsigned long long bm = __ballot(xf == rf);
  if (__popcll(bm) == 1) {
    sl = (int)__ffsll(bm) - 1;
    mn = readlane_f64(x, sl);
  } else {
    union { double d; unsigned u[2]; } v, r;
    v.d = x;
    unsigned hmin = wave_min_bcast_u32(v.u[1]);
    unsigned lc = (v.u[1] == hmin) ? v.u[0] : 0xFFFFFFFFu;
    unsigned lmin = wave_min_bcast_u32(lc);
    unsigned long long b2 = __ballot((v.u[1] == hmin) && (v.u[0] == lmin));
    sl = (int)__ffsll(b2) - 1;
    r.u[0] = lmin; r.u[1] = hmin;
    mn = r.d;
  }
}

// ---------------------------------------------------------------------------
// Full Jonker-Volgenant, ONE WAVE per batch.
// This round (instruction-count diet for the issue-bound pop loop):
//  - exact_min_sl fast path skips the two-stage u32 reduce when the f32
//    wave-min lane is unique (exactness proof in helper comment).
//  - argmin tree carries the column OWNER from a per-Dijkstra register
//    mirror of p (p is constant within one Dijkstra) -> no LDS on the chain.
//  - marking: rec/preg live in per-column LDS, written once by lane 0
//    (uniform address); used-ness is coff[q] in {0,1e18} ADDED to cur
//    (+0.0 is bit-exact; closed cur lands >= 1e18, sentinel minv = 5e17,
//    so closed columns never reopen and never win; vcol keeps full f64
//    precision untouched).
//  - phase 2 passes 2 -> 4 (a pass costs ~nfree row scans; each resolved
//    row saves a several-hundred-pop Dijkstra).
// Dual-update semantics identical to the R2/R4/R5-verified deferred scheme.
// ---------------------------------------------------------------------------
__global__ __launch_bounds__(64) void jv_kernel(const float* __restrict__ Ct,
                                                int* __restrict__ perm) {
  const int b = blockIdx.x;
  const float* C = Ct + (size_t)b * MM * NN;
  __shared__ double u_lds[MM + 1];
  __shared__ int p_lds[NN + 1];
  __shared__ int way_lds[NN + 1];
  __shared__ double rec_lds[NN + 1];
  __shared__ int preg_lds[NN + 1];
  __shared__ int colOwner[NN];
  __shared__ int rowMatched[MM];
  __shared__ int freeL[MM];
  __shared__ int nfree_s;
  __shared__ int cnt_lds[64];
  const int lane = threadIdx.x;
  const int jbase = 8 * lane + 1;   // owned columns, 1-based

  if (lane == 0) u_lds[0] = 0.0;
  for (int t = lane; t <= NN; t += 64) { p_lds[t] = 0; way_lds[t] = 0; }
  for (int t = lane; t < NN; t += 64) colOwner[t] = -1;
  for (int t = lane; t < MM; t += 64) rowMatched[t] = 0;
  asm volatile("s_waitcnt lgkmcnt(0)" ::: "memory");

  // ---- Phase 1: row reduction + greedy claim (depth-2 prefetch) ----
  {
    const float4* r40 = (const float4*)(C);
    const float4* r41 = (const float4*)(C + (size_t)NN);
    float4 ca = r40[2 * lane], cb = r40[2 * lane + 1];
    float4 na = r41[2 * lane], nb = r41[2 * lane + 1];
    for (int r = 0; r < MM; ++r) {
      int rp = (r + 2 < MM) ? (r + 2) : (MM - 1);
      const float4* r4n = (const float4*)(C + (size_t)rp * NN);
      float4 pa = r4n[2 * lane], pb = r4n[2 * lane + 1];
      float c[8] = {ca.x, ca.y, ca.z, ca.w, cb.x, cb.y, cb.z, cb.w};
      float lm = 1e30f; int la = 0;
#pragma unroll
      for (int q = 0; q < 8; ++q)
        if (c[q] < lm) { lm = c[q]; la = 8 * lane + q; }
      float rm = wave_min_bcast_f32(lm);
      unsigned long long bm = __ballot(lm == rm);
      int sl = (int)__ffsll((unsigned long long)bm) - 1;
      int jc = __builtin_amdgcn_readlane(la, sl);
      if (lane == 0) {
        u_lds[r + 1] = (double)rm;
        if (colOwner[jc] < 0) {
          colOwner[jc] = r;
          rowMatched[r] = 1;
          p_lds[jc + 1] = r + 1;
        }
      }
      ca = na; cb = nb; na = pa; nb = pb;
    }
  }
  double vcol[8];
#pragma unroll
  for (int q = 0; q < 8; ++q) vcol[q] = 0.0;
  asm volatile("s_waitcnt lgkmcnt(0)" ::: "memory");

  // ---- build free list (ascending) ----
  if (lane == 0) {
    int n = 0;
    for (int r = 0; r < MM; ++r) if (!rowMatched[r]) freeL[n++] = r;
    nfree_s = n;
  }
  asm volatile("s_waitcnt lgkmcnt(0)" ::: "memory");
  int nfree = nfree_s;   // same LDS addr in all lanes -> uniform

  // ---- Phase 2: augmenting row reduction, 4 passes (next-row prefetch) ----
  for (int pass = 0; pass < 4; ++pass) {
    int prev = nfree; nfree = 0; int k = 0;
    if (prev == 0) continue;
    int i = freeL[0];                                   // uniform LDS read
    {
      const float4* r4p = (const float4*)(C + (size_t)i * NN);
      float4 ca = r4p[2 * lane];
      float4 cb = r4p[2 * lane + 1];
      while (true) {
        const int kn = k + 1;
        const int ig = (kn < prev) ? freeL[kn] : 0;     // uniform prefetch guess
        const float4* r4n = (const float4*)(C + (size_t)ig * NN);
        float4 nca = r4n[2 * lane];
        float4 ncb = r4n[2 * lane + 1];

        float c[8] = {ca.x, ca.y, ca.z, ca.w, cb.x, cb.y, cb.z, cb.w};
        double m1 = 1e18, m2 = 1e18; int a1 = 0;
#pragma unroll
        for (int q = 0; q < 8; ++q) {
          double h = (double)c[q] - vcol[q];   // v <= 0, c >= 0 -> h >= 0
          if (h < m1) { m2 = m1; m1 = h; a1 = 8 * lane + q; }
          else if (h < m2) m2 = h;
        }
        double umin; int sl;
        exact_min_sl(m1, umin, sl);
        int j1 = __builtin_amdgcn_readlane(a1, sl);   // 0-based column
        double cd = (lane == sl) ? m2 : m1;
        double usub; int sl2;
        exact_min_sl(cd, usub, sl2);
        const bool strict = (umin < usub);
        if (strict && (j1 >> 3) == lane) {
          double dec = usub - umin;
#pragma unroll
          for (int qq = 0; qq < 8; ++qq) if (qq == (j1 & 7)) vcol[qq] -= dec;
        }
        const int powner = p_lds[j1 + 1];             // uniform read (pre-write)
        asm volatile("" ::: "memory");                // keep read before write
        const int i0 = powner - 1;
        if (lane == 0) { u_lds[i + 1] = usub; p_lds[j1 + 1] = i + 1; }
        const bool reproc = (i0 >= 0) && strict;
        if (i0 >= 0 && !strict) {
          if (lane == 0) freeL[nfree] = i0;
          nfree++;
        }
        asm volatile("s_waitcnt lgkmcnt(0)" ::: "memory");
        if (reproc) {
          i = i0;                                     // mispredict: reload
          const float4* r4m = (const float4*)(C + (size_t)i * NN);
          ca = r4m[2 * lane];
          cb = r4m[2 * lane + 1];
        } else {
          k = kn;
          if (k >= prev) break;
          i = ig; ca = nca; cb = ncb;                 // prefetch hit
        }
      }
    }
  }

  // ---- Phase 3: Dijkstra/augment for remaining free rows ----
  const int nf3 = nfree;
  for (int fi = 0; fi < nf3; ++fi) {
    const int i = freeL[fi] + 1;   // 1-based row
    if (lane == 0) p_lds[0] = i;   // augment terminator: p[0] = current row
    double minv[8], coff[8];
    int wayr[8], pm[8];
#pragma unroll
    for (int q = 0; q < 8; ++q) { minv[q] = 1e18; coff[q] = 0.0; wayr[q] = 0; }
#pragma unroll
    for (int q = 0; q < 8; ++q) pm[q] = p_lds[jbase + q];   // p const per Dijkstra
    double cum = 0.0;
    int j0 = 0;
    asm volatile("s_waitcnt lgkmcnt(0)" ::: "memory");

    // prologue: loads for the first row of this Dijkstra
    const float4* r4p = (const float4*)(C + (size_t)(i - 1) * NN);
    float4 na = r4p[2 * lane];
    float4 nb = r4p[2 * lane + 1];
    double uu = u_lds[i];

    while (true) {
      float c8[8] = {na.x, na.y, na.z, na.w, nb.x, nb.y, nb.z, nb.w};
      // scan: closed columns get +1e18 via coff -> cur ~1e18 can never beat
      // the 5e17 sentinel nor any open minv; open columns add +0.0 (exact).
#pragma unroll
      for (int q = 0; q < 8; ++q) {
        double cur = (((double)c8[q] - uu) - vcol[q]) + coff[q];
        cur = (cur > 0.0) ? cur : 0.0;   // exact-math nonneg; clamp noise
        bool imp = cur < minv[q];
        minv[q] = imp ? cur : minv[q];
        wayr[q] = imp ? j0 : wayr[q];
      }
      // mask-free tree argmin over 8, carrying col + owner (strict <)
      double m01 = (minv[1] < minv[0]) ? minv[1] : minv[0];
      int    a01 = (minv[1] < minv[0]) ? jbase + 1 : jbase + 0;
      int    p01 = (minv[1] < minv[0]) ? pm[1] : pm[0];
      double m23 = (minv[3] < minv[2]) ? minv[3] : minv[2];
      int    a23 = (minv[3] < minv[2]) ? jbase + 3 : jbase + 2;
      int    p23 = (minv[3] < minv[2]) ? pm[3] : pm[2];
      double m45 = (minv[5] < minv[4]) ? minv[5] : minv[4];
      int    a45 = (minv[5] < minv[4]) ? jbase + 5 : jbase + 4;
      int    p45 = (minv[5] < minv[4]) ? pm[5] : pm[4];
      double m67 = (minv[7] < minv[6]) ? minv[7] : minv[6];
      int    a67 = (minv[7] < minv[6]) ? jbase + 7 : jbase + 6;
      int    p67 = (minv[7] < minv[6]) ? pm[7] : pm[6];
      double m03 = (m23 < m01) ? m23 : m01;
      int    a03 = (m23 < m01) ? a23 : a01;
      int    p03 = (m23 < m01) ? p23 : p01;
      double m47 = (m67 < m45) ? m67 : m45;
      int    a47 = (m67 < m45) ? a67 : a45;
      int    p47 = (m67 < m45) ? p67 : p45;
      double lm = (m47 < m03) ? m47 : m03;
      int    la = (m47 < m03) ? a47 : a03;
      int    lp = (m47 < m03) ? p47 : p03;

      // exact wave min + winner lane (f32 fast path, u32 exact fallback)
      double delta; int sl;
      exact_min_sl(lm, delta, sl);
      int j1 = __builtin_amdgcn_readlane(la, sl);
      int pn = __builtin_amdgcn_readlane(lp, sl);
      cum += delta;
#pragma unroll
      for (int q = 0; q < 8; ++q) minv[q] -= delta;   // sentinels absorb delta
      j0 = j1;
      if (pn == 0) break;

      // issue next row + its potential ASAP (winner known)
      const float4* r4m = (const float4*)(C + (size_t)(pn - 1) * NN);
      na = r4m[2 * lane];
      nb = r4m[2 * lane + 1];
      uu = u_lds[pn];

      // marking: j1 uniform -> (owner lane, slot) are scalars; one lane
      // flips its slot to closed; lane 0 records rec/preg per column in LDS.
      {
        const int ow = (j1 - 1) >> 3;
        const int qs = (j1 - 1) & 7;
#pragma unroll
        for (int q = 0; q < 8; ++q) if (qs == q) {
          bool me = (lane == ow);
          minv[q] = me ? 5e17 : minv[q];    // sentinel: loses to all open cols
          coff[q] = me ? 1e18 : coff[q];    // closed: cur >= 1e18 from now on
        }
        if (lane == 0) { rec_lds[j1] = cum; preg_lds[j1] = pn; }
      }
    }

    if (lane == 0) u_lds[i] += cum;
    asm volatile("s_waitcnt lgkmcnt(0)" ::: "memory");
#pragma unroll
    for (int q = 0; q < 8; ++q) {
      way_lds[jbase + q] = wayr[q];    // flush reg-held way for the path walk
      if (coff[q] != 0.0) {            // closed this Dijkstra
        double d = cum - rec_lds[jbase + q];
        int pr = preg_lds[jbase + q];
        vcol[q] -= d;
        u_lds[pr] += d;   // popped rows distinct -> no conflicts
      }
    }
    asm volatile("s_waitcnt lgkmcnt(0)" ::: "memory");
    if (lane == 0) {
      int jj = j0;
      while (jj != 0) { int jp = way_lds[jj]; p_lds[jj] = p_lds[jp]; jj = jp; }
    }
    asm volatile("s_waitcnt lgkmcnt(0)" ::: "memory");
  }

  // perm = matched cols (assigned seq1 rows) ascending, then unmatched ascending
  int mask = 0, cnt = 0;
#pragma unroll
  for (int q = 0; q < 8; ++q)
    if (p_lds[jbase + q] != 0) { mask |= 1 << q; cnt++; }
  cnt_lds[lane] = cnt;
  asm volatile("s_waitcnt lgkmcnt(0)" ::: "memory");
  int pre = 0;
  for (int l = 0; l < 64; ++l) { int cl = cnt_lds[l]; if (l < lane) pre += cl; }
  int mpos = pre;
  int upos = MM + (8 * lane - pre);
#pragma unroll
  for (int q = 0; q < 8; ++q) {
    int col = 8 * lane + q;
    if ((mask >> q) & 1) perm[b * NN + mpos++] = col;
    else                 perm[b * NN + upos++] = col;
  }
}

// ---------------------------------------------------------------------------
// Gather: out[b,i,:] = seq1[b, perm[b][i], :]
// ---------------------------------------------------------------------------
__global__ __launch_bounds__(256) void gather_kernel(const float* __restrict__ s1,
                                                     const int* __restrict__ perm,
                                                     float* __restrict__ out) {
  const int bi = blockIdx.x;
  const int b = bi >> 9;
  const int src = perm[bi];
  const float4* sp = (const float4*)(s1 + ((size_t)b * NN + src) * DD);
  float4* dp = (float4*)(out + (size_t)bi * DD);
  for (int t = threadIdx.x; t < DD / 4; t += 256) dp[t] = sp[t];
}

extern "C" void kernel_launch(void* const* d_in, const int* in_sizes, int n_in,
                              void* d_out, int out_size, void* d_ws, size_t ws_size,
                              hipStream_t stream) {
  const float* s1 = (const float*)d_in[0];
  const float* s2 = (const float*)d_in[1];
  float* out = (float*)d_out;
  float* Ct = (float*)d_out;       // staged cost matrix, overwritten by gather
  int* perm = (int*)d_ws;

  dim3 cg(NN / 64, MM / 64, BB);
  cost_kernel<<<cg, 256, 0, stream>>>(s1, s2, Ct);
  jv_kernel<<<BB, 64, 0, stream>>>(Ct, perm);
  gather_kernel<<<BB * NN, 256, 0, stream>>>(s1, perm, out);
}

// Round 4
// 6976.969 us; speedup vs baseline: 1.0034x; 1.0034x over previous
//
#include <hip/hip_runtime.h>
#include <math.h>

#define BB 16
#define NN 512   // seq1 rows = columns of the transposed LSA problem
#define MM 448   // seq2 rows = rows of the transposed LSA problem
#define DD 1536

// ---------------------------------------------------------------------------
// Cost kernel: Ct[b][j][i] = ||seq1[b,i,:] - seq2[b,j,:]||  (float32)
// Unchanged from the passing round-1/2/4/5 version.
// ---------------------------------------------------------------------------
constexpr int TK = 32;

__global__ __launch_bounds__(256) void cost_kernel(const float* __restrict__ s1,
                                                   const float* __restrict__ s2,
                                                   float* __restrict__ Ct) {
  __shared__ float As[TK][68];
  __shared__ float Bs[TK][68];
  const int b = blockIdx.z;
  const int ibase = blockIdx.x * 64;
  const int jbase = blockIdx.y * 64;
  const int tid = threadIdx.x;
  const float* s1b = s1 + ((size_t)b * NN + ibase) * DD;
  const float* s2b = s2 + ((size_t)b * MM + jbase) * DD;
  const int ix = (tid & 15) * 4;
  const int jy = (tid >> 4) * 4;
  double acc[16];
#pragma unroll
  for (int t = 0; t < 16; ++t) acc[t] = 0.0;

  for (int k0 = 0; k0 < DD; k0 += TK) {
#pragma unroll
    for (int rep = 0; rep < 2; ++rep) {
      int idx = tid + rep * 256;
      int r = idx >> 3;
      int c4 = (idx & 7) * 4;
      float4 a = *(const float4*)(s1b + (size_t)r * DD + k0 + c4);
      As[c4 + 0][r] = a.x; As[c4 + 1][r] = a.y; As[c4 + 2][r] = a.z; As[c4 + 3][r] = a.w;
      float4 bb = *(const float4*)(s2b + (size_t)r * DD + k0 + c4);
      Bs[c4 + 0][r] = bb.x; Bs[c4 + 1][r] = bb.y; Bs[c4 + 2][r] = bb.z; Bs[c4 + 3][r] = bb.w;
    }
    __syncthreads();
    float pacc[16];
#pragma unroll
    for (int t = 0; t < 16; ++t) pacc[t] = 0.f;
#pragma unroll 8
    for (int kk = 0; kk < TK; ++kk) {
      float4 av = *(const float4*)&As[kk][ix];
      float4 bv = *(const float4*)&Bs[kk][jy];
      float a[4] = {av.x, av.y, av.z, av.w};
      float bq[4] = {bv.x, bv.y, bv.z, bv.w};
#pragma unroll
      for (int t = 0; t < 4; ++t)
#pragma unroll
        for (int q = 0; q < 4; ++q) {
          float d = a[t] - bq[q];
          pacc[t * 4 + q] = fmaf(d, d, pacc[t * 4 + q]);
        }
    }
#pragma unroll
    for (int t = 0; t < 16; ++t) acc[t] += (double)pacc[t];
    __syncthreads();
  }
#pragma unroll
  for (int t = 0; t < 4; ++t)
#pragma unroll
    for (int q = 0; q < 4; ++q) {
      int i = ibase + ix + t;
      int jj = jbase + jy + q;
      float d2 = (float)acc[t * 4 + q];
      Ct[((size_t)b * MM + jj) * NN + i] = sqrtf(fmaxf(d2, 0.f));
    }
}

// ---------------------------------------------------------------------------
// Cross-lane reduction primitives (DPP shr 1/2/4/8 + bcast 15/31, readlane 63
// broadcast — control pattern verified bit-exact in rounds 1-5, absmax = 0).
// ---------------------------------------------------------------------------
__device__ __forceinline__ unsigned wave_min_bcast_u32(unsigned x) {
  int v = (int)x;
#define ST(C) { int o = __builtin_amdgcn_update_dpp(-1, v, C, 0xF, 0xF, false); \
                v = ((unsigned)o < (unsigned)v) ? o : v; }
  ST(0x111) ST(0x112) ST(0x114) ST(0x118) ST(0x142) ST(0x143)
#undef ST
  return (unsigned)__builtin_amdgcn_readlane(v, 63);
}

__device__ __forceinline__ float wave_min_bcast_f32(float x) {
  union FU { float f; int i; };
  FU v; v.f = x;
  const int INFB = 0x7f7fffff;   // FLT_MAX bit pattern
#define DPP1(CTRL) { FU o; \
  o.i = __builtin_amdgcn_update_dpp(INFB, v.i, CTRL, 0xF, 0xF, false); \
  if (o.f < v.f) v.f = o.f; }
  DPP1(0x111) DPP1(0x112) DPP1(0x114) DPP1(0x118) DPP1(0x142) DPP1(0x143)
#undef DPP1
  FU r; r.i = __builtin_amdgcn_readlane(v.i, 63);
  return r.f;
}

__device__ __forceinline__ double readlane_f64(double x, int sl) {
  union { double d; int i[2]; } v, r;
  v.d = x;
  r.i[0] = __builtin_amdgcn_readlane(v.i[0], sl);
  r.i[1] = __builtin_amdgcn_readlane(v.i[1], sl);
  return r.d;
}

// Exact wave min of NONNEGATIVE f64 + winner lane (lowest lane among exact
// ties). FAST PATH: f64->f32 rounding is monotone, so a UNIQUE lane at the
// f32 wave-min provably holds the exact f64 min -> readlane its f64 bits
// (exact delta, exact winner; an exact f64 tie would produce an f32 tie, so
// uniqueness at f32 also implies the lowest-lane tiebreak is trivially met).
// Ties at f32 fall back to the verified two-stage u32 reduce. The (mn, sl)
// pair is BIT-IDENTICAL to the always-u32 version -> decision-identical.
__device__ __forceinline__ void exact_min_sl(double x, double& mn, int& sl) {
  float xf = (float)x;
  float rf = wave_min_bcast_f32(xf);
  unsigned long long bm = __ballot(xf == rf);
  if (__popcll(bm) == 1) {
    sl = (int)__ffsll(bm) - 1;
    mn = readlane_f64(x, sl);
  } else {
    union { double d; unsigned u[2]; } v, r;
    v.d = x;
    unsigned hmin = wave_min_bcast_u32(v.u[1]);
    unsigned lc = (v.u[1] == hmin) ? v.u[0] : 0xFFFFFFFFu;
    unsigned lmin = wave_min_bcast_u32(lc);
    unsigned long long b2 = __ballot((v.u[1] == hmin) && (v.u[0] == lmin));
    sl = (int)__ffsll(b2) - 1;
    r.u[0] = lmin; r.u[1] = hmin;
    mn = r.d;
  }
}

// ---------------------------------------------------------------------------
// Full Jonker-Volgenant, ONE WAVE per batch.
// R4 = R2's VERIFIED decision stream (phase 1 f32-rowmin claim on raw c,
// NO column init — manufactured exact-zero ties in R3 flipped the matched
// set under degeneracy) + decision-identical pop-loop restructure:
//  - f32 pre-reduce predicts winner -> next-row load issued IMMEDIATELY
//    (R1's overlap, which R2 lost);
//  - unique f32 min => provably exact winner & delta (skip u32 reduce);
//    tie => verified u32 fallback, reload only if winner differs;
//  - winner owner via p_lds[la] gather (overlaps the f32 DPP chain);
//  - R2's cheap marking kept (coff sentinels, lane-0 rec/preg, wayr regs).
// Dual-update semantics identical to the verified deferred scheme.
// ---------------------------------------------------------------------------
__global__ __launch_bounds__(64) void jv_kernel(const float* __restrict__ Ct,
                                                int* __restrict__ perm) {
  const int b = blockIdx.x;
  const float* C = Ct + (size_t)b * MM * NN;
  __shared__ double u_lds[MM + 1];
  __shared__ int p_lds[NN + 1];
  __shared__ int way_lds[NN + 1];
  __shared__ double rec_lds[NN + 1];
  __shared__ int preg_lds[NN + 1];
  __shared__ int colOwner[NN];
  __shared__ int rowMatched[MM];
  __shared__ int freeL[MM];
  __shared__ int nfree_s;
  __shared__ int cnt_lds[64];
  const int lane = threadIdx.x;
  const int jbase = 8 * lane + 1;   // owned columns, 1-based

  if (lane == 0) u_lds[0] = 0.0;
  for (int t = lane; t <= NN; t += 64) { p_lds[t] = 0; way_lds[t] = 0; }
  for (int t = lane; t < NN; t += 64) colOwner[t] = -1;
  for (int t = lane; t < MM; t += 64) rowMatched[t] = 0;
  asm volatile("s_waitcnt lgkmcnt(0)" ::: "memory");

  // ---- Phase 1: row reduction + greedy claim (depth-2 prefetch) ----
  // (verified R1/R2 version: f32 rowmin over raw c, claim argmin of c)
  {
    const float4* r40 = (const float4*)(C);
    const float4* r41 = (const float4*)(C + (size_t)NN);
    float4 ca = r40[2 * lane], cb = r40[2 * lane + 1];
    float4 na = r41[2 * lane], nb = r41[2 * lane + 1];
    for (int r = 0; r < MM; ++r) {
      int rp = (r + 2 < MM) ? (r + 2) : (MM - 1);
      const float4* r4n = (const float4*)(C + (size_t)rp * NN);
      float4 pa = r4n[2 * lane], pb = r4n[2 * lane + 1];
      float c[8] = {ca.x, ca.y, ca.z, ca.w, cb.x, cb.y, cb.z, cb.w};
      float lm = 1e30f; int la = 0;
#pragma unroll
      for (int q = 0; q < 8; ++q)
        if (c[q] < lm) { lm = c[q]; la = 8 * lane + q; }
      float rm = wave_min_bcast_f32(lm);
      unsigned long long bm = __ballot(lm == rm);
      int sl = (int)__ffsll((unsigned long long)bm) - 1;
      int jc = __builtin_amdgcn_readlane(la, sl);
      if (lane == 0) {
        u_lds[r + 1] = (double)rm;
        if (colOwner[jc] < 0) {
          colOwner[jc] = r;
          rowMatched[r] = 1;
          p_lds[jc + 1] = r + 1;
        }
      }
      ca = na; cb = nb; na = pa; nb = pb;
    }
  }
  double vcol[8];
#pragma unroll
  for (int q = 0; q < 8; ++q) vcol[q] = 0.0;
  asm volatile("s_waitcnt lgkmcnt(0)" ::: "memory");

  // ---- build free list (ascending) ----
  if (lane == 0) {
    int n = 0;
    for (int r = 0; r < MM; ++r) if (!rowMatched[r]) freeL[n++] = r;
    nfree_s = n;
  }
  asm volatile("s_waitcnt lgkmcnt(0)" ::: "memory");
  int nfree = nfree_s;   // same LDS addr in all lanes -> uniform

  // ---- Phase 2: augmenting row reduction, 4 passes (next-row prefetch) ----
  for (int pass = 0; pass < 4; ++pass) {
    int prev = nfree; nfree = 0; int k = 0;
    if (prev == 0) continue;
    int i = freeL[0];                                   // uniform LDS read
    {
      const float4* r4p = (const float4*)(C + (size_t)i * NN);
      float4 ca = r4p[2 * lane];
      float4 cb = r4p[2 * lane + 1];
      while (true) {
        const int kn = k + 1;
        const int ig = (kn < prev) ? freeL[kn] : 0;     // uniform prefetch guess
        const float4* r4n = (const float4*)(C + (size_t)ig * NN);
        float4 nca = r4n[2 * lane];
        float4 ncb = r4n[2 * lane + 1];

        float c[8] = {ca.x, ca.y, ca.z, ca.w, cb.x, cb.y, cb.z, cb.w};
        double m1 = 1e18, m2 = 1e18; int a1 = 0;
#pragma unroll
        for (int q = 0; q < 8; ++q) {
          double h = (double)c[q] - vcol[q];   // v <= 0, c >= 0 -> h >= 0
          if (h < m1) { m2 = m1; m1 = h; a1 = 8 * lane + q; }
          else if (h < m2) m2 = h;
        }
        double umin; int sl;
        exact_min_sl(m1, umin, sl);
        int j1 = __builtin_amdgcn_readlane(a1, sl);   // 0-based column
        double cd = (lane == sl) ? m2 : m1;
        double usub; int sl2;
        exact_min_sl(cd, usub, sl2);
        const bool strict = (umin < usub);
        if (strict && (j1 >> 3) == lane) {
          double dec = usub - umin;
#pragma unroll
          for (int qq = 0; qq < 8; ++qq) if (qq == (j1 & 7)) vcol[qq] -= dec;
        }
        const int powner = p_lds[j1 + 1];             // uniform read (pre-write)
        asm volatile("" ::: "memory");                // keep read before write
        const int i0 = powner - 1;
        if (lane == 0) { u_lds[i + 1] = usub; p_lds[j1 + 1] = i + 1; }
        const bool reproc = (i0 >= 0) && strict;
        if (i0 >= 0 && !strict) {
          if (lane == 0) freeL[nfree] = i0;
          nfree++;
        }
        asm volatile("s_waitcnt lgkmcnt(0)" ::: "memory");
        if (reproc) {
          i = i0;                                     // mispredict: reload
          const float4* r4m = (const float4*)(C + (size_t)i * NN);
          ca = r4m[2 * lane];
          cb = r4m[2 * lane + 1];
        } else {
          k = kn;
          if (k >= prev) break;
          i = ig; ca = nca; cb = ncb;                 // prefetch hit
        }
      }
    }
  }

  // ---- Phase 3: Dijkstra/augment for remaining free rows ----
  const int nf3 = nfree;
  for (int fi = 0; fi < nf3; ++fi) {
    const int i = freeL[fi] + 1;   // 1-based row
    if (lane == 0) p_lds[0] = i;   // augment terminator: p[0] = current row
    double minv[8], coff[8];
    int wayr[8];
#pragma unroll
    for (int q = 0; q < 8; ++q) { minv[q] = 1e18; coff[q] = 0.0; wayr[q] = 0; }
    double cum = 0.0;
    int j0 = 0;
    asm volatile("s_waitcnt lgkmcnt(0)" ::: "memory");

    // prologue: loads for the first row of this Dijkstra
    const float4* r4p = (const float4*)(C + (size_t)(i - 1) * NN);
    float4 na = r4p[2 * lane];
    float4 nb = r4p[2 * lane + 1];
    double uu = u_lds[i];

    while (true) {
      float c8[8] = {na.x, na.y, na.z, na.w, nb.x, nb.y, nb.z, nb.w};
      // scan: closed columns get +1e18 via coff -> cur ~1e18 can never beat
      // the 5e17 sentinel nor any open minv; open columns add +0.0 (exact).
#pragma unroll
      for (int q = 0; q < 8; ++q) {
        double cur = (((double)c8[q] - uu) - vcol[q]) + coff[q];
        cur = (cur > 0.0) ? cur : 0.0;   // exact-math nonneg; clamp noise
        bool imp = cur < minv[q];
        minv[q] = imp ? cur : minv[q];
        wayr[q] = imp ? j0 : wayr[q];
      }
      // mask-free tree argmin over 8 (strict < keeps lowest index)
      double m01 = (minv[1] < minv[0]) ? minv[1] : minv[0];
      int    a01 = (minv[1] < minv[0]) ? jbase + 1 : jbase + 0;
      double m23 = (minv[3] < minv[2]) ? minv[3] : minv[2];
      int    a23 = (minv[3] < minv[2]) ? jbase + 3 : jbase + 2;
      double m45 = (minv[5] < minv[4]) ? minv[5] : minv[4];
      int    a45 = (minv[5] < minv[4]) ? jbase + 5 : jbase + 4;
      double m67 = (minv[7] < minv[6]) ? minv[7] : minv[6];
      int    a67 = (minv[7] < minv[6]) ? jbase + 7 : jbase + 6;
      double m03 = (m23 < m01) ? m23 : m01;
      int    a03 = (m23 < m01) ? a23 : a01;
      double m47 = (m67 < m45) ? m67 : m45;
      int    a47 = (m67 < m45) ? a67 : a45;
      double lm = (m47 < m03) ? m47 : m03;
      int    la = (m47 < m03) ? a47 : a03;

      // per-lane owner candidate gather; overlaps the f32 DPP chain below
      // (p is constant within one Dijkstra)
      int pcand = p_lds[la];

      // ---- f32 pre-reduce: predicted winner -> ISSUE next-row load NOW ----
      float lmf = (float)lm;
      float rmf = wave_min_bcast_f32(lmf);
      unsigned long long bmf = __ballot(lmf == rmf);
      int slp = (int)__ffsll(bmf) - 1;
      int j1 = __builtin_amdgcn_readlane(la, slp);
      int pn = __builtin_amdgcn_readlane(pcand, slp);
      int rs = (pn > 0) ? (pn - 1) : 0;
      const float4* r4s = (const float4*)(C + (size_t)rs * NN);
      float4 sca = r4s[2 * lane];
      float4 scb = r4s[2 * lane + 1];
      double uus = u_lds[pn];          // u_lds[0] defined (=0), pn uniform

      double delta;
      if (__popcll(bmf) == 1) {
        // unique f32 min -> provably the exact winner; loads already correct
        delta = readlane_f64(lm, slp);
      } else {
        // exact two-stage u32 fallback (rare); reload only if winner differs
        union { double d; unsigned u[2]; } lv, dd;
        lv.d = lm;
        unsigned hmin = wave_min_bcast_u32(lv.u[1]);
        unsigned lc = (lv.u[1] == hmin) ? lv.u[0] : 0xFFFFFFFFu;
        unsigned lmin = wave_min_bcast_u32(lc);
        unsigned long long bm2 = __ballot((lv.u[1] == hmin) && (lv.u[0] == lmin));
        int sl = (int)__ffsll(bm2) - 1;
        dd.u[0] = lmin; dd.u[1] = hmin;
        delta = dd.d;
        if (sl != slp) {
          j1 = __builtin_amdgcn_readlane(la, sl);
          pn = __builtin_amdgcn_readlane(pcand, sl);
          int rs2 = (pn > 0) ? (pn - 1) : 0;
          const float4* r4m = (const float4*)(C + (size_t)rs2 * NN);
          sca = r4m[2 * lane];
          scb = r4m[2 * lane + 1];
          uus = u_lds[pn];
        }
      }
      cum += delta;
#pragma unroll
      for (int q = 0; q < 8; ++q) minv[q] -= delta;   // sentinels absorb delta
      j0 = j1;
      if (pn == 0) break;

      // adopt the in-flight next row
      na = sca; nb = scb; uu = uus;

      // marking: j1 uniform -> (owner lane, slot) are scalars; one lane
      // flips its slot to closed; lane 0 records rec/preg per column in LDS.
      {
        const int ow = (j1 - 1) >> 3;
        const int qs = (j1 - 1) & 7;
#pragma unroll
        for (int q = 0; q < 8; ++q) if (qs == q) {
          bool me = (lane == ow);
          minv[q] = me ? 5e17 : minv[q];    // sentinel: loses to all open cols
          coff[q] = me ? 1e18 : coff[q];    // closed: cur >= 1e18 from now on
        }
        if (lane == 0) { rec_lds[j1] = cum; preg_lds[j1] = pn; }
      }
    }

    if (lane == 0) u_lds[i] += cum;
    asm volatile("s_waitcnt lgkmcnt(0)" ::: "memory");
#pragma unroll
    for (int q = 0; q < 8; ++q) {
      way_lds[jbase + q] = wayr[q];    // flush reg-held way for the path walk
      if (coff[q] != 0.0) {            // closed this Dijkstra
        double d = cum - rec_lds[jbase + q];
        int pr = preg_lds[jbase + q];
        vcol[q] -= d;
        u_lds[pr] += d;   // popped rows distinct -> no conflicts
      }
    }
    asm volatile("s_waitcnt lgkmcnt(0)" ::: "memory");
    if (lane == 0) {
      int jj = j0;
      while (jj != 0) { int jp = way_lds[jj]; p_lds[jj] = p_lds[jp]; jj = jp; }
    }
    asm volatile("s_waitcnt lgkmcnt(0)" ::: "memory");
  }

  // perm = matched cols (assigned seq1 rows) ascending, then unmatched ascending
  int mask = 0, cnt = 0;
#pragma unroll
  for (int q = 0; q < 8; ++q)
    if (p_lds[jbase + q] != 0) { mask |= 1 << q; cnt++; }
  cnt_lds[lane] = cnt;
  asm volatile("s_waitcnt lgkmcnt(0)" ::: "memory");
  int pre = 0;
  for (int l = 0; l < 64; ++l) { int cl = cnt_lds[l]; if (l < lane) pre += cl; }
  int mpos = pre;
  int upos = MM + (8 * lane - pre);
#pragma unroll
  for (int q = 0; q < 8; ++q) {
    int col = 8 * lane + q;
    if ((mask >> q) & 1) perm[b * NN + mpos++] = col;
    else                 perm[b * NN + upos++] = col;
  }
}

// ---------------------------------------------------------------------------
// Gather: out[b,i,:] = seq1[b, perm[b][i], :]
// ---------------------------------------------------------------------------
__global__ __launch_bounds__(256) void gather_kernel(const float* __restrict__ s1,
                                                     const int* __restrict__ perm,
                                                     float* __restrict__ out) {
  const int bi = blockIdx.x;
  const int b = bi >> 9;
  const int src = perm[bi];
  const float4* sp = (const float4*)(s1 + ((size_t)b * NN + src) * DD);
  float4* dp = (float4*)(out + (size_t)bi * DD);
  for (int t = threadIdx.x; t < DD / 4; t += 256) dp[t] = sp[t];
}

extern "C" void kernel_launch(void* const* d_in, const int* in_sizes, int n_in,
                              void* d_out, int out_size, void* d_ws, size_t ws_size,
                              hipStream_t stream) {
  const float* s1 = (const float*)d_in[0];
  const float* s2 = (const float*)d_in[1];
  float* out = (float*)d_out;
  float* Ct = (float*)d_out;       // staged cost matrix, overwritten by gather
  int* perm = (int*)d_ws;

  dim3 cg(NN / 64, MM / 64, BB);
  cost_kernel<<<cg, 256, 0, stream>>>(s1, s2, Ct);
  jv_kernel<<<BB, 64, 0, stream>>>(Ct, perm);
  gather_kernel<<<BB * NN, 256, 0, stream>>>(s1, perm, out);
}

// Round 5
// 6423.813 us; speedup vs baseline: 1.0898x; 1.0861x over previous
//
#include <hip/hip_runtime.h>
#include <math.h>

#define BB 16
#define NN 512   // seq1 rows = columns of the transposed LSA problem
#define MM 448   // seq2 rows = rows of the transposed LSA problem
#define DD 1536

// ---------------------------------------------------------------------------
// Cost kernel: Ct[b][j][i] = ||seq1[b,i,:] - seq2[b,j,:]||  (float32)
// Unchanged from the passing rounds.
// ---------------------------------------------------------------------------
constexpr int TK = 32;

__global__ __launch_bounds__(256) void cost_kernel(const float* __restrict__ s1,
                                                   const float* __restrict__ s2,
                                                   float* __restrict__ Ct) {
  __shared__ float As[TK][68];
  __shared__ float Bs[TK][68];
  const int b = blockIdx.z;
  const int ibase = blockIdx.x * 64;
  const int jbase = blockIdx.y * 64;
  const int tid = threadIdx.x;
  const float* s1b = s1 + ((size_t)b * NN + ibase) * DD;
  const float* s2b = s2 + ((size_t)b * MM + jbase) * DD;
  const int ix = (tid & 15) * 4;
  const int jy = (tid >> 4) * 4;
  double acc[16];
#pragma unroll
  for (int t = 0; t < 16; ++t) acc[t] = 0.0;

  for (int k0 = 0; k0 < DD; k0 += TK) {
#pragma unroll
    for (int rep = 0; rep < 2; ++rep) {
      int idx = tid + rep * 256;
      int r = idx >> 3;
      int c4 = (idx & 7) * 4;
      float4 a = *(const float4*)(s1b + (size_t)r * DD + k0 + c4);
      As[c4 + 0][r] = a.x; As[c4 + 1][r] = a.y; As[c4 + 2][r] = a.z; As[c4 + 3][r] = a.w;
      float4 bb = *(const float4*)(s2b + (size_t)r * DD + k0 + c4);
      Bs[c4 + 0][r] = bb.x; Bs[c4 + 1][r] = bb.y; Bs[c4 + 2][r] = bb.z; Bs[c4 + 3][r] = bb.w;
    }
    __syncthreads();
    float pacc[16];
#pragma unroll
    for (int t = 0; t < 16; ++t) pacc[t] = 0.f;
#pragma unroll 8
    for (int kk = 0; kk < TK; ++kk) {
      float4 av = *(const float4*)&As[kk][ix];
      float4 bv = *(const float4*)&Bs[kk][jy];
      float a[4] = {av.x, av.y, av.z, av.w};
      float bq[4] = {bv.x, bv.y, bv.z, bv.w};
#pragma unroll
      for (int t = 0; t < 4; ++t)
#pragma unroll
        for (int q = 0; q < 4; ++q) {
          float d = a[t] - bq[q];
          pacc[t * 4 + q] = fmaf(d, d, pacc[t * 4 + q]);
        }
    }
#pragma unroll
    for (int t = 0; t < 16; ++t) acc[t] += (double)pacc[t];
    __syncthreads();
  }
#pragma unroll
  for (int t = 0; t < 4; ++t)
#pragma unroll
    for (int q = 0; q < 4; ++q) {
      int i = ibase + ix + t;
      int jj = jbase + jy + q;
      float d2 = (float)acc[t * 4 + q];
      Ct[((size_t)b * MM + jj) * NN + i] = sqrtf(fmaxf(d2, 0.f));
    }
}

// ---------------------------------------------------------------------------
// Cross-lane reduction primitives (DPP shr 1/2/4/8 + bcast 15/31, readlane 63
// broadcast — control pattern verified bit-exact across passing rounds).
// ---------------------------------------------------------------------------
__device__ __forceinline__ unsigned wave_min_bcast_u32(unsigned x) {
  int v = (int)x;
#define ST(C) { int o = __builtin_amdgcn_update_dpp(-1, v, C, 0xF, 0xF, false); \
                v = ((unsigned)o < (unsigned)v) ? o : v; }
  ST(0x111) ST(0x112) ST(0x114) ST(0x118) ST(0x142) ST(0x143)
#undef ST
  return (unsigned)__builtin_amdgcn_readlane(v, 63);
}

// Exact f64 min over the wave for NONNEGATIVE doubles: bit pattern of a
// nonneg double is order-preserving as u64 -> two u32 min stages (hi, then
// lo among hi-winners). Verified bit-exact (R1 phase 2).
__device__ __forceinline__ double wave_min_bcast_f64_fast(double x) {
  union DU { double d; unsigned u[2]; };
  DU v; v.d = x;
  unsigned hmin = wave_min_bcast_u32(v.u[1]);
  unsigned lc = (v.u[1] == hmin) ? v.u[0] : 0xFFFFFFFFu;
  unsigned lmin = wave_min_bcast_u32(lc);
  DU r; r.u[0] = lmin; r.u[1] = hmin;
  return r.d;
}

__device__ __forceinline__ float wave_min_bcast_f32(float x) {
  union FU { float f; int i; };
  FU v; v.f = x;
  const int INFB = 0x7f7fffff;   // FLT_MAX bit pattern
#define DPP1(CTRL) { FU o; \
  o.i = __builtin_amdgcn_update_dpp(INFB, v.i, CTRL, 0xF, 0xF, false); \
  if (o.f < v.f) v.f = o.f; }
  DPP1(0x111) DPP1(0x112) DPP1(0x114) DPP1(0x118) DPP1(0x142) DPP1(0x143)
#undef DPP1
  FU r; r.i = __builtin_amdgcn_readlane(v.i, 63);
  return r.f;
}

// ---------------------------------------------------------------------------
// Full Jonker-Volgenant, ONE WAVE per batch.
// R5 = component-wise recombination driven by the R1/R2/R4 evidence:
//  - Phases 1+2: R1 VERBATIM (2 passes, straight f64_fast reduces — the
//    4-pass + f32-prereduce variants added ~17% VALU work, R2/R4 regression).
//  - Phase 3: R1's spec-prefetch (f32 pre-reduce -> issue next-row loads
//    BEFORE the exact reduce) + R1's straight-line ALWAYS-u32 exact reduce
//    (no branchy fast path), with R2/R4's verified cheap scan/marking:
//    coff in {0,1e18} added to cur (replaces the !used predication),
//    one-slot sentinel marking, lane-0 rec/preg in LDS, wayr registers.
//  - fmin for minv-merge and tree value selects (bit-exact: operands are
//    >= +0 or sentinels, never NaN, never -0; the clamp keeps its verified
//    ternary form because -0 would corrupt the u32 bit-order reduce).
// Every (delta, j1, pn) decision is bit-identical to the verified streams.
// ---------------------------------------------------------------------------
__global__ __launch_bounds__(64) void jv_kernel(const float* __restrict__ Ct,
                                                int* __restrict__ perm) {
  const int b = blockIdx.x;
  const float* C = Ct + (size_t)b * MM * NN;
  __shared__ double u_lds[MM + 1];
  __shared__ int p_lds[NN + 1];
  __shared__ int way_lds[NN + 1];
  __shared__ double rec_lds[NN + 1];
  __shared__ int preg_lds[NN + 1];
  __shared__ int colOwner[NN];
  __shared__ int rowMatched[MM];
  __shared__ int freeL[MM];
  __shared__ int nfree_s;
  __shared__ int cnt_lds[64];
  const int lane = threadIdx.x;
  const int jbase = 8 * lane + 1;   // owned columns, 1-based

  if (lane == 0) u_lds[0] = 0.0;
  for (int t = lane; t <= NN; t += 64) { p_lds[t] = 0; way_lds[t] = 0; }
  for (int t = lane; t < NN; t += 64) colOwner[t] = -1;
  for (int t = lane; t < MM; t += 64) rowMatched[t] = 0;
  asm volatile("s_waitcnt lgkmcnt(0)" ::: "memory");

  // ---- Phase 1: row reduction + greedy claim (depth-2 prefetch) ----
  {
    const float4* r40 = (const float4*)(C);
    const float4* r41 = (const float4*)(C + (size_t)NN);
    float4 ca = r40[2 * lane], cb = r40[2 * lane + 1];
    float4 na = r41[2 * lane], nb = r41[2 * lane + 1];
    for (int r = 0; r < MM; ++r) {
      int rp = (r + 2 < MM) ? (r + 2) : (MM - 1);
      const float4* r4n = (const float4*)(C + (size_t)rp * NN);
      float4 pa = r4n[2 * lane], pb = r4n[2 * lane + 1];
      float c[8] = {ca.x, ca.y, ca.z, ca.w, cb.x, cb.y, cb.z, cb.w};
      float lm = 1e30f; int la = 0;
#pragma unroll
      for (int q = 0; q < 8; ++q)
        if (c[q] < lm) { lm = c[q]; la = 8 * lane + q; }
      float rm = wave_min_bcast_f32(lm);
      unsigned long long bm = __ballot(lm == rm);
      int sl = (int)__ffsll((unsigned long long)bm) - 1;
      int jc = __builtin_amdgcn_readlane(la, sl);
      if (lane == 0) {
        u_lds[r + 1] = (double)rm;
        if (colOwner[jc] < 0) {
          colOwner[jc] = r;
          rowMatched[r] = 1;
          p_lds[jc + 1] = r + 1;
        }
      }
      ca = na; cb = nb; na = pa; nb = pb;
    }
  }
  double vcol[8];
#pragma unroll
  for (int q = 0; q < 8; ++q) vcol[q] = 0.0;
  asm volatile("s_waitcnt lgkmcnt(0)" ::: "memory");

  // ---- build free list (ascending) ----
  if (lane == 0) {
    int n = 0;
    for (int r = 0; r < MM; ++r) if (!rowMatched[r]) freeL[n++] = r;
    nfree_s = n;
  }
  asm volatile("s_waitcnt lgkmcnt(0)" ::: "memory");
  int nfree = nfree_s;   // same LDS addr in all lanes -> uniform

  // ---- Phase 2: augmenting row reduction, 2 passes (next-row prefetch) ----
  for (int pass = 0; pass < 2; ++pass) {
    int prev = nfree; nfree = 0; int k = 0;
    if (prev == 0) continue;
    int i = freeL[0];                                   // uniform LDS read
    {
      const float4* r4p = (const float4*)(C + (size_t)i * NN);
      float4 ca = r4p[2 * lane];
      float4 cb = r4p[2 * lane + 1];
      while (true) {
        const int kn = k + 1;
        const int ig = (kn < prev) ? freeL[kn] : 0;     // uniform prefetch guess
        const float4* r4n = (const float4*)(C + (size_t)ig * NN);
        float4 nca = r4n[2 * lane];
        float4 ncb = r4n[2 * lane + 1];

        float c[8] = {ca.x, ca.y, ca.z, ca.w, cb.x, cb.y, cb.z, cb.w};
        double m1 = 1e18, m2 = 1e18; int a1 = 0;
#pragma unroll
        for (int q = 0; q < 8; ++q) {
          double h = (double)c[q] - vcol[q];   // v <= 0, c >= 0 -> h >= 0
          if (h < m1) { m2 = m1; m1 = h; a1 = 8 * lane + q; }
          else if (h < m2) m2 = h;
        }
        double umin = wave_min_bcast_f64_fast(m1);
        unsigned long long bm = __ballot(m1 == umin);
        int sl = (int)__ffsll((unsigned long long)bm) - 1;
        int j1 = __builtin_amdgcn_readlane(a1, sl);   // 0-based column
        double cd = (lane == sl) ? m2 : m1;
        double usub = wave_min_bcast_f64_fast(cd);
        const bool strict = (umin < usub);
        if (strict && (j1 >> 3) == lane) {
          double dec = usub - umin;
#pragma unroll
          for (int qq = 0; qq < 8; ++qq) if (qq == (j1 & 7)) vcol[qq] -= dec;
        }
        const int powner = p_lds[j1 + 1];             // uniform read (pre-write)
        asm volatile("" ::: "memory");                // keep read before write
        const int i0 = powner - 1;
        if (lane == 0) { u_lds[i + 1] = usub; p_lds[j1 + 1] = i + 1; }
        const bool reproc = (i0 >= 0) && strict;
        if (i0 >= 0 && !strict) {
          if (lane == 0) freeL[nfree] = i0;
          nfree++;
        }
        asm volatile("s_waitcnt lgkmcnt(0)" ::: "memory");
        if (reproc) {
          i = i0;                                     // mispredict: reload
          const float4* r4m = (const float4*)(C + (size_t)i * NN);
          ca = r4m[2 * lane];
          cb = r4m[2 * lane + 1];
        } else {
          k = kn;
          if (k >= prev) break;
          i = ig; ca = nca; cb = ncb;                 // prefetch hit
        }
      }
    }
  }

  // ---- Phase 3: Dijkstra/augment for remaining free rows ----
  const int nf3 = nfree;
  for (int fi = 0; fi < nf3; ++fi) {
    const int i = freeL[fi] + 1;   // 1-based row
    if (lane == 0) p_lds[0] = i;   // augment terminator: p[0] = current row
    double minv[8], coff[8];
    int wayr[8];
#pragma unroll
    for (int q = 0; q < 8; ++q) { minv[q] = 1e18; coff[q] = 0.0; wayr[q] = 0; }
    double cum = 0.0;
    int j0 = 0;
    asm volatile("s_waitcnt lgkmcnt(0)" ::: "memory");

    // prologue: loads for the first row of this Dijkstra
    const float4* r4p = (const float4*)(C + (size_t)(i - 1) * NN);
    float4 na = r4p[2 * lane];
    float4 nb = r4p[2 * lane + 1];
    double uu = u_lds[i];

    while (true) {
      float c8[8] = {na.x, na.y, na.z, na.w, nb.x, nb.y, nb.z, nb.w};
      // scan: closed columns get +1e18 via coff -> cur ~1e18 can never beat
      // the 5e17 sentinel nor any open minv; open columns add +0.0 (exact).
#pragma unroll
      for (int q = 0; q < 8; ++q) {
        double cur = (((double)c8[q] - uu) - vcol[q]) + coff[q];
        cur = (cur > 0.0) ? cur : 0.0;   // verified clamp form (never -0)
        bool imp = cur < minv[q];
        wayr[q] = imp ? j0 : wayr[q];
        minv[q] = fmin(cur, minv[q]);    // bit-exact vs cndmask select
      }
      // mask-free tree argmin over 8 (strict < keeps lowest index);
      // values via v_min_f64, indices via cmp+cndmask
      double m01 = fmin(minv[0], minv[1]);
      int    a01 = (minv[1] < minv[0]) ? jbase + 1 : jbase + 0;
      double m23 = fmin(minv[2], minv[3]);
      int    a23 = (minv[3] < minv[2]) ? jbase + 3 : jbase + 2;
      double m45 = fmin(minv[4], minv[5]);
      int    a45 = (minv[5] < minv[4]) ? jbase + 5 : jbase + 4;
      double m67 = fmin(minv[6], minv[7]);
      int    a67 = (minv[7] < minv[6]) ? jbase + 7 : jbase + 6;
      double m03 = fmin(m01, m23);
      int    a03 = (m23 < m01) ? a23 : a01;
      double m47 = fmin(m45, m67);
      int    a47 = (m67 < m45) ? a67 : a45;
      double lm = fmin(m03, m47);
      int    la = (m47 < m03) ? a47 : a03;

      // per-lane owner candidate gather; overlaps the f32 DPP chain below
      // (p is constant within one Dijkstra)
      int pcand = p_lds[la];

      // ---- f32 pre-reduce: predicted winner -> ISSUE next-row load NOW ----
      float lmf = (float)lm;
      float rmf = wave_min_bcast_f32(lmf);
      unsigned long long bmf = __ballot(lmf == rmf);
      int slp = (int)__ffsll(bmf) - 1;
      int pnf = __builtin_amdgcn_readlane(pcand, slp);
      int rs = (pnf > 0) ? (pnf - 1) : 0;
      const float4* r4s = (const float4*)(C + (size_t)rs * NN);
      float4 sca = r4s[2 * lane];
      float4 scb = r4s[2 * lane + 1];
      double uus = u_lds[pnf];          // u_lds[0] defined (=0), pnf uniform

      // ---- ALWAYS exact two-stage u32 reduce (straight-line, R1) ----
      union DU { double d; unsigned u[2]; } lv, dd;
      lv.d = lm;
      unsigned hmin = wave_min_bcast_u32(lv.u[1]);
      unsigned lc = (lv.u[1] == hmin) ? lv.u[0] : 0xFFFFFFFFu;
      unsigned lmin = wave_min_bcast_u32(lc);
      unsigned long long bm2 = __ballot((lv.u[1] == hmin) && (lv.u[0] == lmin));
      int sl = (int)__ffsll(bm2) - 1;
      int j1 = __builtin_amdgcn_readlane(la, sl);
      int pn = __builtin_amdgcn_readlane(pcand, sl);
      dd.u[0] = lmin; dd.u[1] = hmin;
      double delta = dd.d;
      cum += delta;
#pragma unroll
      for (int q = 0; q < 8; ++q) minv[q] -= delta;   // sentinels absorb delta
      j0 = j1;
      if (pn == 0) break;

      if (pn == pnf) {                 // prediction hit: loads already in flight
        na = sca; nb = scb; uu = uus;
      } else {                         // rare f32-tie mispredict: reload exact
        const float4* r4m = (const float4*)(C + (size_t)(pn - 1) * NN);
        na = r4m[2 * lane];
        nb = r4m[2 * lane + 1];
        uu = u_lds[pn];
      }

      // marking: j1 uniform -> (owner lane, slot) are scalars; one lane
      // flips its slot to closed; lane 0 records rec/preg per column in LDS.
      {
        const int ow = (j1 - 1) >> 3;
        const int qs = (j1 - 1) & 7;
#pragma unroll
        for (int q = 0; q < 8; ++q) if (qs == q) {
          bool me = (lane == ow);
          minv[q] = me ? 5e17 : minv[q];    // sentinel: loses to all open cols
          coff[q] = me ? 1e18 : coff[q];    // closed: cur >= 1e18 from now on
        }
        if (lane == 0) { rec_lds[j1] = cum; preg_lds[j1] = pn; }
      }
    }

    if (lane == 0) u_lds[i] += cum;
    asm volatile("s_waitcnt lgkmcnt(0)" ::: "memory");
#pragma unroll
    for (int q = 0; q < 8; ++q) {
      way_lds[jbase + q] = wayr[q];    // flush reg-held way for the path walk
      if (coff[q] != 0.0) {            // closed this Dijkstra
        double d = cum - rec_lds[jbase + q];
        int pr = preg_lds[jbase + q];
        vcol[q] -= d;
        u_lds[pr] += d;   // popped rows distinct -> no conflicts
      }
    }
    asm volatile("s_waitcnt lgkmcnt(0)" ::: "memory");
    if (lane == 0) {
      int jj = j0;
      while (jj != 0) { int jp = way_lds[jj]; p_lds[jj] = p_lds[jp]; jj = jp; }
    }
    asm volatile("s_waitcnt lgkmcnt(0)" ::: "memory");
  }

  // perm = matched cols (assigned seq1 rows) ascending, then unmatched ascending
  int mask = 0, cnt = 0;
#pragma unroll
  for (int q = 0; q < 8; ++q)
    if (p_lds[jbase + q] != 0) { mask |= 1 << q; cnt++; }
  cnt_lds[lane] = cnt;
  asm volatile("s_waitcnt lgkmcnt(0)" ::: "memory");
  int pre = 0;
  for (int l = 0; l < 64; ++l) { int cl = cnt_lds[l]; if (l < lane) pre += cl; }
  int mpos = pre;
  int upos = MM + (8 * lane - pre);
#pragma unroll
  for (int q = 0; q < 8; ++q) {
    int col = 8 * lane + q;
    if ((mask >> q) & 1) perm[b * NN + mpos++] = col;
    else                 perm[b * NN + upos++] = col;
  }
}

// ---------------------------------------------------------------------------
// Gather: out[b,i,:] = seq1[b, perm[b][i], :]
// ---------------------------------------------------------------------------
__global__ __launch_bounds__(256) void gather_kernel(const float* __restrict__ s1,
                                                     const int* __restrict__ perm,
                                                     float* __restrict__ out) {
  const int bi = blockIdx.x;
  const int b = bi >> 9;
  const int src = perm[bi];
  const float4* sp = (const float4*)(s1 + ((size_t)b * NN + src) * DD);
  float4* dp = (float4*)(out + (size_t)bi * DD);
  for (int t = threadIdx.x; t < DD / 4; t += 256) dp[t] = sp[t];
}

extern "C" void kernel_launch(void* const* d_in, const int* in_sizes, int n_in,
                              void* d_out, int out_size, void* d_ws, size_t ws_size,
                              hipStream_t stream) {
  const float* s1 = (const float*)d_in[0];
  const float* s2 = (const float*)d_in[1];
  float* out = (float*)d_out;
  float* Ct = (float*)d_out;       // staged cost matrix, overwritten by gather
  int* perm = (int*)d_ws;

  dim3 cg(NN / 64, MM / 64, BB);
  cost_kernel<<<cg, 256, 0, stream>>>(s1, s2, Ct);
  jv_kernel<<<BB, 64, 0, stream>>>(Ct, perm);
  gather_kernel<<<BB * NN, 256, 0, stream>>>(s1, perm, out);
}